// Round 4
// baseline (208.548 us; speedup 1.0000x reference)
//
#include <hip/hip_runtime.h>
#include <cstdint>

constexpr int N_FEAT  = 8;
constexpr int E_FEAT  = 4;
constexpr int NUM_IN  = 2 * (N_FEAT + 2) + E_FEAT + 1;  // 25
constexpr int NUM_OUT = 2 * N_FEAT + E_FEAT;            // 20

__global__ __launch_bounds__(256) void edge_mlp(
    const float* __restrict__ r,
    const float* __restrict__ a_data,
    const float* __restrict__ a_mat,
    const float* __restrict__ a_inf,
    const float* __restrict__ b_data,
    const float* __restrict__ b_mat,
    const float* __restrict__ b_inf,
    const float* __restrict__ e_data,
    const float* __restrict__ W1,   // (25,25) row-major fp32
    const float* __restrict__ B1,   // (25,)
    const float* __restrict__ W2,   // (20,25) row-major
    const float* __restrict__ B2,   // (20,)
    float*       __restrict__ out,  // fp32, 3 segments concatenated
    int E) {
  int e = blockIdx.x * blockDim.x + threadIdx.x;
  if (e >= E) return;

  // ---- gather the 25 fp32 input features (coalesced, vectorized) ----
  const float4* a4 = reinterpret_cast<const float4*>(a_data) + 2 * (size_t)e;
  const float4* b4 = reinterpret_cast<const float4*>(b_data) + 2 * (size_t)e;
  float4 a0 = a4[0], a1 = a4[1];
  float4 b0 = b4[0], b1v = b4[1];
  float4 ev = reinterpret_cast<const float4*>(e_data)[e];

  float x[NUM_IN];
  x[0]  = r[e];
  x[1]  = a0.x; x[2]  = a0.y; x[3]  = a0.z; x[4]  = a0.w;
  x[5]  = a1.x; x[6]  = a1.y; x[7]  = a1.z; x[8]  = a1.w;
  x[9]  = a_mat[e];
  x[10] = a_inf[e];
  x[11] = b0.x; x[12] = b0.y; x[13] = b0.z; x[14] = b0.w;
  x[15] = b1v.x; x[16] = b1v.y; x[17] = b1v.z; x[18] = b1v.w;
  x[19] = b_mat[e];
  x[20] = b_inf[e];
  x[21] = ev.x; x[22] = ev.y; x[23] = ev.z; x[24] = ev.w;

  // ---- layer 1: h = relu(W1 @ x + b1); weights wave-uniform -> SGPR loads ----
  float h[NUM_IN];
#pragma unroll
  for (int j = 0; j < NUM_IN; ++j) {
    float acc = B1[j];
    const float* wr = W1 + j * NUM_IN;
#pragma unroll
    for (int k = 0; k < NUM_IN; ++k) acc = fmaf(wr[k], x[k], acc);
    h[j] = fmaxf(acc, 0.0f);
  }

  // ---- layer 2: y = relu(W2 @ h + b2) ----
  float y[NUM_OUT];
#pragma unroll
  for (int j = 0; j < NUM_OUT; ++j) {
    float acc = B2[j];
    const float* wr = W2 + j * NUM_IN;
#pragma unroll
    for (int k = 0; k < NUM_IN; ++k) acc = fmaf(wr[k], h[k], acc);
    y[j] = fmaxf(acc, 0.0f);
  }

  // ---- store fp32 into the 3 concatenated output segments ----
  float4* o0 = reinterpret_cast<float4*>(out) + 2 * (size_t)e;          // (E,8)
  o0[0] = make_float4(y[0], y[1], y[2],  y[3]);
  o0[1] = make_float4(y[4], y[5], y[6],  y[7]);
  float4* o1 = reinterpret_cast<float4*>(out + (size_t)8 * E) + 2 * (size_t)e;  // (E,8)
  o1[0] = make_float4(y[8],  y[9],  y[10], y[11]);
  o1[1] = make_float4(y[12], y[13], y[14], y[15]);
  reinterpret_cast<float4*>(out + (size_t)16 * E)[e] =                  // (E,4)
      make_float4(y[16], y[17], y[18], y[19]);
}

extern "C" void kernel_launch(void* const* d_in, const int* in_sizes, int n_in,
                              void* d_out, int out_size, void* d_ws, size_t ws_size,
                              hipStream_t stream) {
  const float* r      = (const float*)d_in[0];
  const float* a_data = (const float*)d_in[1];
  const float* a_mat  = (const float*)d_in[2];
  const float* a_inf  = (const float*)d_in[3];
  const float* b_data = (const float*)d_in[4];
  const float* b_mat  = (const float*)d_in[5];
  const float* b_inf  = (const float*)d_in[6];
  const float* e_data = (const float*)d_in[7];
  const float* W1     = (const float*)d_in[8];
  const float* B1     = (const float*)d_in[9];
  const float* W2     = (const float*)d_in[10];
  const float* B2     = (const float*)d_in[11];
  int E = in_sizes[0];

  edge_mlp<<<(E + 255) / 256, 256, 0, stream>>>(
      r, a_data, a_mat, a_inf, b_data, b_mat, b_inf, e_data,
      W1, B1, W2, B2, (float*)d_out, E);
}

// Round 5
// 206.623 us; speedup vs baseline: 1.0093x; 1.0093x over previous
//
#include <hip/hip_runtime.h>
#include <cstdint>

constexpr int N_FEAT  = 8;
constexpr int E_FEAT  = 4;
constexpr int NUM_IN  = 2 * (N_FEAT + 2) + E_FEAT + 1;  // 25
constexpr int NUM_OUT = 2 * N_FEAT + E_FEAT;            // 20

// amdgpu_waves_per_eu(4,4): pin occupancy target to 4 waves/EU (16 waves/CU,
// 128-VGPR budget). Without it the allocator chased 8 waves/EU (28 VGPRs!)
// and serviced x[25]/h[25]/y[20] from memory (remat + scratch) -> VMEM-bound
// at 76 us with VALUBusy 40%.
__global__ __launch_bounds__(256)
__attribute__((amdgpu_waves_per_eu(4, 4)))
void edge_mlp(
    const float* __restrict__ r,
    const float* __restrict__ a_data,
    const float* __restrict__ a_mat,
    const float* __restrict__ a_inf,
    const float* __restrict__ b_data,
    const float* __restrict__ b_mat,
    const float* __restrict__ b_inf,
    const float* __restrict__ e_data,
    const float* __restrict__ W1,   // (25,25) row-major fp32
    const float* __restrict__ B1,   // (25,)
    const float* __restrict__ W2,   // (20,25) row-major
    const float* __restrict__ B2,   // (20,)
    float*       __restrict__ out,  // fp32, 3 segments concatenated
    int E) {
  int e = blockIdx.x * blockDim.x + threadIdx.x;
  if (e >= E) return;

  // ---- gather the 25 fp32 input features (coalesced, vectorized) ----
  const float4* a4 = reinterpret_cast<const float4*>(a_data) + 2 * (size_t)e;
  const float4* b4 = reinterpret_cast<const float4*>(b_data) + 2 * (size_t)e;
  float4 a0 = a4[0], a1 = a4[1];
  float4 b0 = b4[0], b1v = b4[1];
  float4 ev = reinterpret_cast<const float4*>(e_data)[e];

  float x[NUM_IN];
  x[0]  = r[e];
  x[1]  = a0.x; x[2]  = a0.y; x[3]  = a0.z; x[4]  = a0.w;
  x[5]  = a1.x; x[6]  = a1.y; x[7]  = a1.z; x[8]  = a1.w;
  x[9]  = a_mat[e];
  x[10] = a_inf[e];
  x[11] = b0.x; x[12] = b0.y; x[13] = b0.z; x[14] = b0.w;
  x[15] = b1v.x; x[16] = b1v.y; x[17] = b1v.z; x[18] = b1v.w;
  x[19] = b_mat[e];
  x[20] = b_inf[e];
  x[21] = ev.x; x[22] = ev.y; x[23] = ev.z; x[24] = ev.w;

  // ---- layer 1: h = relu(W1 @ x + b1); weights wave-uniform -> SGPR loads ----
  float h[NUM_IN];
#pragma unroll
  for (int j = 0; j < NUM_IN; ++j) {
    float acc = B1[j];
    const float* wr = W1 + j * NUM_IN;
#pragma unroll
    for (int k = 0; k < NUM_IN; ++k) acc = fmaf(wr[k], x[k], acc);
    h[j] = fmaxf(acc, 0.0f);
  }

  // ---- layer 2: y = relu(W2 @ h + b2) ----
  float y[NUM_OUT];
#pragma unroll
  for (int j = 0; j < NUM_OUT; ++j) {
    float acc = B2[j];
    const float* wr = W2 + j * NUM_IN;
#pragma unroll
    for (int k = 0; k < NUM_IN; ++k) acc = fmaf(wr[k], h[k], acc);
    y[j] = fmaxf(acc, 0.0f);
  }

  // ---- store fp32 into the 3 concatenated output segments ----
  float4* o0 = reinterpret_cast<float4*>(out) + 2 * (size_t)e;          // (E,8)
  o0[0] = make_float4(y[0], y[1], y[2],  y[3]);
  o0[1] = make_float4(y[4], y[5], y[6],  y[7]);
  float4* o1 = reinterpret_cast<float4*>(out + (size_t)8 * E) + 2 * (size_t)e;  // (E,8)
  o1[0] = make_float4(y[8],  y[9],  y[10], y[11]);
  o1[1] = make_float4(y[12], y[13], y[14], y[15]);
  reinterpret_cast<float4*>(out + (size_t)16 * E)[e] =                  // (E,4)
      make_float4(y[16], y[17], y[18], y[19]);
}

extern "C" void kernel_launch(void* const* d_in, const int* in_sizes, int n_in,
                              void* d_out, int out_size, void* d_ws, size_t ws_size,
                              hipStream_t stream) {
  const float* r      = (const float*)d_in[0];
  const float* a_data = (const float*)d_in[1];
  const float* a_mat  = (const float*)d_in[2];
  const float* a_inf  = (const float*)d_in[3];
  const float* b_data = (const float*)d_in[4];
  const float* b_mat  = (const float*)d_in[5];
  const float* b_inf  = (const float*)d_in[6];
  const float* e_data = (const float*)d_in[7];
  const float* W1     = (const float*)d_in[8];
  const float* B1     = (const float*)d_in[9];
  const float* W2     = (const float*)d_in[10];
  const float* B2     = (const float*)d_in[11];
  int E = in_sizes[0];

  edge_mlp<<<(E + 255) / 256, 256, 0, stream>>>(
      r, a_data, a_mat, a_inf, b_data, b_mat, b_inf, e_data,
      W1, B1, W2, B2, (float*)d_out, E);
}